// Round 1
// baseline (271.302 us; speedup 1.0000x reference)
//
#include <hip/hip_runtime.h>
#include <math.h>
#include <stdint.h>

// Problem constants (fixed by the reference)
#define S_LEN  8192
#define DMODEL 512
#define NBATCH 4

// GEMM tiling
constexpr int BM = 128, BN = 128, BK = 32;
constexpr int PK = 40;               // padded LDS row stride (elements); 80 B, 16B-aligned
constexpr int NKSPLIT = 8;           // split-K chunks for gemm_m
constexpr int KCHUNK = S_LEN / NKSPLIT;  // 1024

typedef short bfrag  __attribute__((ext_vector_type(8)));   // 8 bf16 (4 VGPRs)
typedef short short8 __attribute__((ext_vector_type(8)));
typedef short short4v __attribute__((ext_vector_type(4)));
typedef float facc   __attribute__((ext_vector_type(4)));   // 4 fp32 acc

__device__ __forceinline__ short f2bf(float f) {
  union { float f; unsigned u; } c; c.f = f;
  unsigned u = c.u;
  u = (u + 0x7fffu + ((u >> 16) & 1u)) >> 16;   // RNE
  return (short)(unsigned short)u;
}

__device__ __forceinline__ void atomAddF(float* p, float v) {
  unsafeAtomicAdd(p, v);   // global_atomic_add_f32 on gfx950
}

// ---------------------------------------------------------------------------
// Kernel 1: M[b][d'][d] = sum_t w_t * h[b][t][d'] * e[b][t][d]   (split-K, atomics)
// also v[b][d] = sum_t w_t * e[b][t][d]  (accumulated by mt==0 blocks)
// MFMA view: A[m=d'][k=t] = h[t][d'] (transposed-stage), B[k=t][n=d] = w_t*e[t][d]
// ---------------------------------------------------------------------------
__global__ __launch_bounds__(256, 2) void gemm_m_kernel(
    const float* __restrict__ h, const float* __restrict__ e,
    float* __restrict__ Mws, float* __restrict__ vws)
{
  __shared__ short Al[BM * PK];
  __shared__ short Bl[BN * PK];

  const int blk = blockIdx.x;          // grid = NBATCH * NKSPLIT * 16 = 512
  const int nt  = blk & 3;
  const int mt  = (blk >> 2) & 3;
  const int kt  = (blk >> 4) & (NKSPLIT - 1);
  const int bb  = blk >> 7;

  const int tid = threadIdx.x;
  const int m   = tid & 127;           // staging: d'/d offset within tile
  const int kh  = tid >> 7;            // staging: which 16-row half of BK

  const int wv   = tid >> 6;           // wave 0..3 -> 2x2 of 64x64 subtiles
  const int wm   = wv >> 1, wn = wv & 1;
  const int lane = tid & 63;
  const int lm   = lane & 15, q = lane >> 4;

  const float* hb = h + (size_t)bb * S_LEN * DMODEL;
  const float* eb = e + (size_t)bb * S_LEN * DMODEL;

  facc acc[4][4];
#pragma unroll
  for (int i = 0; i < 4; ++i)
#pragma unroll
    for (int j = 0; j < 4; ++j) acc[i][j] = (facc){0.f, 0.f, 0.f, 0.f};

  float vacc = 0.f;
  const float lnA = -(float)M_PI / (float)S_LEN;   // log(alpha)

  const int tstart = kt * KCHUNK, tend = tstart + KCHUNK;
  for (int t0 = tstart; t0 < tend; t0 += BK) {
    const int tb = t0 + kh * 16;
    float av[16], bv[16];
    const float* hrow = hb + (size_t)tb * DMODEL + mt * BM + m;
    const float* erow = eb + (size_t)tb * DMODEL + nt * BN + m;
#pragma unroll
    for (int r = 0; r < 16; ++r) av[r] = hrow[(size_t)r * DMODEL];
#pragma unroll
    for (int r = 0; r < 16; ++r) bv[r] = erow[(size_t)r * DMODEL];
#pragma unroll
    for (int r = 0; r < 16; ++r) {
      const float w = __expf((float)(S_LEN - 1 - (tb + r)) * lnA);  // alpha^(S-1-t)
      bv[r] *= w;
      if (mt == 0) vacc += bv[r];
    }

    __syncthreads();   // previous iteration's frag reads done
    short8 p;
#pragma unroll
    for (int r = 0; r < 8; ++r) p[r] = f2bf(av[r]);
    *(short8*)&Al[m * PK + kh * 16] = p;
#pragma unroll
    for (int r = 0; r < 8; ++r) p[r] = f2bf(av[r + 8]);
    *(short8*)&Al[m * PK + kh * 16 + 8] = p;
#pragma unroll
    for (int r = 0; r < 8; ++r) p[r] = f2bf(bv[r]);
    *(short8*)&Bl[m * PK + kh * 16] = p;
#pragma unroll
    for (int r = 0; r < 8; ++r) p[r] = f2bf(bv[r + 8]);
    *(short8*)&Bl[m * PK + kh * 16 + 8] = p;
    __syncthreads();

    bfrag af[4], bf[4];
#pragma unroll
    for (int i = 0; i < 4; ++i)
      af[i] = *(const bfrag*)&Al[(wm * 64 + i * 16 + lm) * PK + q * 8];
#pragma unroll
    for (int j = 0; j < 4; ++j)
      bf[j] = *(const bfrag*)&Bl[(wn * 64 + j * 16 + lm) * PK + q * 8];
#pragma unroll
    for (int i = 0; i < 4; ++i)
#pragma unroll
      for (int j = 0; j < 4; ++j)
        acc[i][j] = __builtin_amdgcn_mfma_f32_16x16x32_bf16(af[i], bf[j], acc[i][j], 0, 0, 0);
  }

  float* Mb = Mws + (size_t)bb * DMODEL * DMODEL;
#pragma unroll
  for (int i = 0; i < 4; ++i)
#pragma unroll
    for (int j = 0; j < 4; ++j)
#pragma unroll
      for (int r = 0; r < 4; ++r) {
        const int row = mt * BM + wm * 64 + i * 16 + q * 4 + r;   // d'
        const int col = nt * BN + wn * 64 + j * 16 + lm;          // d
        atomAddF(&Mb[(size_t)row * DMODEL + col], acc[i][j][r]);
      }

  if (mt == 0) atomAddF(&vws[bb * DMODEL + nt * BN + m], vacc);
}

// ---------------------------------------------------------------------------
// Kernel 2: C[b][s][d] = sum_{d'} W[s][d'] * M[b][d'][d] + bias[s]*v[b][d]
// A[m=s][k=d'] = W (K-contiguous, vector-staged); B[k=d'][n=d] = M (transposed-stage)
// ---------------------------------------------------------------------------
__global__ __launch_bounds__(256) void gemm_c_kernel(
    const float* __restrict__ Wmat, const float* __restrict__ bias,
    const float* __restrict__ Mws, const float* __restrict__ vws,
    float* __restrict__ out)
{
  __shared__ short Wl[BM * PK];
  __shared__ short Ml[BN * PK];

  const int blk = blockIdx.x;          // grid = NBATCH * 16 = 64
  const int nt  = blk & 3;
  const int mt  = (blk >> 2) & 3;
  const int bb  = blk >> 4;

  const int tid = threadIdx.x;
  const int n   = tid & 127;           // M staging
  const int kh  = tid >> 7;
  const int arow  = tid >> 3;          // W staging: 0..31
  const int akseg = tid & 7;

  const int wv   = tid >> 6;
  const int wm   = wv >> 1, wn = wv & 1;
  const int lane = tid & 63;
  const int lm   = lane & 15, q = lane >> 4;

  const float* Mb = Mws + (size_t)bb * DMODEL * DMODEL;

  facc acc[4][4];
#pragma unroll
  for (int i = 0; i < 4; ++i)
#pragma unroll
    for (int j = 0; j < 4; ++j) acc[i][j] = (facc){0.f, 0.f, 0.f, 0.f};

  for (int k0 = 0; k0 < DMODEL; k0 += BK) {
    float4 wreg[4];
#pragma unroll
    for (int pp = 0; pp < 4; ++pp) {
      const int row = pp * 32 + arow;
      wreg[pp] = *(const float4*)&Wmat[(size_t)(mt * BM + row) * DMODEL + k0 + akseg * 4];
    }
    float mv[16];
    const float* mrow = Mb + (size_t)(k0 + kh * 16) * DMODEL + nt * BN + n;
#pragma unroll
    for (int r = 0; r < 16; ++r) mv[r] = mrow[(size_t)r * DMODEL];

    __syncthreads();
#pragma unroll
    for (int pp = 0; pp < 4; ++pp) {
      const int row = pp * 32 + arow;
      short4v pw;
      pw[0] = f2bf(wreg[pp].x); pw[1] = f2bf(wreg[pp].y);
      pw[2] = f2bf(wreg[pp].z); pw[3] = f2bf(wreg[pp].w);
      *(short4v*)&Wl[row * PK + akseg * 4] = pw;
    }
    short8 pm;
#pragma unroll
    for (int r = 0; r < 8; ++r) pm[r] = f2bf(mv[r]);
    *(short8*)&Ml[n * PK + kh * 16] = pm;
#pragma unroll
    for (int r = 0; r < 8; ++r) pm[r] = f2bf(mv[r + 8]);
    *(short8*)&Ml[n * PK + kh * 16 + 8] = pm;
    __syncthreads();

    bfrag af[4], bf[4];
#pragma unroll
    for (int i = 0; i < 4; ++i)
      af[i] = *(const bfrag*)&Wl[(wm * 64 + i * 16 + lm) * PK + q * 8];
#pragma unroll
    for (int j = 0; j < 4; ++j)
      bf[j] = *(const bfrag*)&Ml[(wn * 64 + j * 16 + lm) * PK + q * 8];
#pragma unroll
    for (int i = 0; i < 4; ++i)
#pragma unroll
      for (int j = 0; j < 4; ++j)
        acc[i][j] = __builtin_amdgcn_mfma_f32_16x16x32_bf16(af[i], bf[j], acc[i][j], 0, 0, 0);
  }

#pragma unroll
  for (int i = 0; i < 4; ++i)
#pragma unroll
    for (int j = 0; j < 4; ++j)
#pragma unroll
      for (int r = 0; r < 4; ++r) {
        const int row = mt * BM + wm * 64 + i * 16 + q * 4 + r;   // s
        const int col = nt * BN + wn * 64 + j * 16 + lm;          // d
        const float cv = acc[i][j][r] + bias[row] * vws[bb * DMODEL + col];
        out[((size_t)bb * DMODEL + row) * DMODEL + col] = cv;
      }
}

// ---------------------------------------------------------------------------
extern "C" void kernel_launch(void* const* d_in, const int* in_sizes, int n_in,
                              void* d_out, int out_size, void* d_ws, size_t ws_size,
                              hipStream_t stream) {
  const float* h    = (const float*)d_in[0];   // (4, 8192, 512) fp32
  const float* e    = (const float*)d_in[1];   // (4, 8192, 512) fp32
  const float* Wmat = (const float*)d_in[2];   // (512, 512) fp32
  const float* bias = (const float*)d_in[3];   // (512,) fp32
  float* out = (float*)d_out;                  // (4, 512, 512) fp32

  float* Mws = (float*)d_ws;                                            // 4 MB
  float* vws = (float*)((char*)d_ws + (size_t)NBATCH * DMODEL * DMODEL * sizeof(float)); // 8 KB
  const size_t zero_bytes = (size_t)NBATCH * DMODEL * DMODEL * sizeof(float)
                          + (size_t)NBATCH * DMODEL * sizeof(float);
  hipMemsetAsync(d_ws, 0, zero_bytes, stream);

  gemm_m_kernel<<<NBATCH * NKSPLIT * 16, 256, 0, stream>>>(h, e, Mws, vws);
  gemm_c_kernel<<<NBATCH * 16, 256, 0, stream>>>(Wmat, bias, Mws, vws, out);
}

// Round 3
// 252.328 us; speedup vs baseline: 1.0752x; 1.0752x over previous
//
#include <hip/hip_runtime.h>
#include <math.h>
#include <stdint.h>

// Problem constants (fixed by the reference)
#define S_LEN  8192
#define DMODEL 512
#define NBATCH 4

// gemm_m tiling
constexpr int BM = 128, BN = 128, BK = 32;
constexpr int PK = 40;                    // padded LDS row stride (shorts); 80 B = 16B-aligned
constexpr int NKSPLIT = 16;               // split-K chunks for gemm_m
constexpr int KCHUNK = S_LEN / NKSPLIT;   // 512 -> 16 K-iters per block

// gemm_c tiling
constexpr int CBM = 64, CBN = 64, CBK = 32;
constexpr int CSPLIT = 4;                 // split-K over d'
constexpr int CKC = DMODEL / CSPLIT;      // 128 -> 4 K-iters per block

typedef short bfrag  __attribute__((ext_vector_type(8)));   // 8 bf16 (4 VGPRs)
typedef short short8 __attribute__((ext_vector_type(8)));
typedef float facc   __attribute__((ext_vector_type(4)));   // 4 fp32 acc

__device__ __forceinline__ short f2bf(float f) {
  union { float f; unsigned u; } c; c.f = f;
  unsigned u = c.u;
  u = (u + 0x7fffu + ((u >> 16) & 1u)) >> 16;   // RNE
  return (short)(unsigned short)u;
}

__device__ __forceinline__ void atomAddF(float* p, float v) {
  unsafeAtomicAdd(p, v);   // global_atomic_add_f32
}

// ---------------------------------------------------------------------------
// Kernel 1: M[b][d'][d] = sum_t w_t * h[b][t][d'] * e[b][t][d]   (split-K, atomics)
// also v[b][d] = sum_t w_t * e[b][t][d]  (accumulated by mt==0 staging-B threads)
// Staging: threads 0..127 stage A (h), threads 128..255 stage B (e).
// Each stager: 8x global_load_dwordx4 = 4 cols x 8 t-rows, register transpose,
// 4x b128 LDS writes into [col][t] layout.
// ---------------------------------------------------------------------------
__global__ __launch_bounds__(256, 4) void gemm_m_kernel(
    const float* __restrict__ h, const float* __restrict__ e,
    float* __restrict__ Mws, float* __restrict__ vws)
{
  __shared__ short Al[BM * PK];
  __shared__ short Bl[BN * PK];

  const int blk = blockIdx.x;          // grid = NBATCH * NKSPLIT * 16 = 1024
  const int nt  = blk & 3;
  const int mt  = (blk >> 2) & 3;
  const int kt  = (blk >> 4) & (NKSPLIT - 1);
  const int bb  = blk >> 8;

  const int tid   = threadIdx.x;
  const bool isB  = (tid >= 128);      // wave-uniform (waves 2,3)
  const int hid   = tid & 127;
  const int col4  = (hid & 31) * 4;    // 4-col group within the 128-wide tile
  const int trow  = hid >> 5;          // 0..3 -> t-rows trow*8 .. trow*8+7

  const int wv   = tid >> 6;           // wave 0..3 -> 2x2 of 64x64 subtiles
  const int wm   = wv >> 1, wn = wv & 1;
  const int lane = tid & 63;
  const int lm   = lane & 15, q = lane >> 4;

  // staging source: A-threads read h (cols = mt*BM..), B-threads read e (cols = nt*BN..)
  const float* src = (isB ? e : h) + (size_t)bb * S_LEN * DMODEL
                   + (isB ? nt * BN : mt * BM) + col4;
  short* ldst = (isB ? Bl : Al) + col4 * PK + trow * 8;

  facc acc[4][4];
#pragma unroll
  for (int i = 0; i < 4; ++i)
#pragma unroll
    for (int j = 0; j < 4; ++j) acc[i][j] = (facc){0.f, 0.f, 0.f, 0.f};

  const float lnA = -(float)M_PI / (float)S_LEN;   // log(alpha), negative
  const int tstart = kt * KCHUNK, tend = tstart + KCHUNK;

  // decay weights: w(t) = alpha^(S-1-t); per-thread base at t = tstart + trow*8,
  // stepped multiplicatively by alpha^(-BK) per iter; per-row factors alpha^(-r).
  // NOTE: plain float math — do NOT route through readfirstlane (int-typed builtin
  // silently value-converts floats; that was R2's correctness bug).
  float wbase = __expf(lnA * (float)(S_LEN - 1 - tstart - trow * 8));
  const float stepw = __expf(-lnA * (float)BK);    // alpha^(-32) ≈ 1.01234
  float cr[8];
#pragma unroll
  for (int r = 0; r < 8; ++r)
    cr[r] = __expf(-lnA * (float)r);               // alpha^(-r)

  float4 vacc4 = {0.f, 0.f, 0.f, 0.f};

  for (int t0 = tstart; t0 < tend; t0 += BK) {
    // ---- global loads: 8 x dwordx4 (4 cols x 8 t-rows) ----
    float4 ld[8];
    const float* p = src + (size_t)(t0 + trow * 8) * DMODEL;
#pragma unroll
    for (int r = 0; r < 8; ++r) ld[r] = *(const float4*)(p + (size_t)r * DMODEL);

    // ---- scale (B only) + accumulate v ----
    if (isB) {
#pragma unroll
      for (int r = 0; r < 8; ++r) {
        const float w = wbase * cr[r];
        ld[r].x *= w; ld[r].y *= w; ld[r].z *= w; ld[r].w *= w;
      }
      if (mt == 0) {
#pragma unroll
        for (int r = 0; r < 8; ++r) {
          vacc4.x += ld[r].x; vacc4.y += ld[r].y;
          vacc4.z += ld[r].z; vacc4.w += ld[r].w;
        }
      }
    }
    wbase *= stepw;

    __syncthreads();   // previous iteration's frag reads done
    // ---- register transpose -> bf16 -> 4x b128 LDS writes ([col][t] layout) ----
#pragma unroll
    for (int c = 0; c < 4; ++c) {
      short8 pk;
      pk[0] = f2bf(c == 0 ? ld[0].x : c == 1 ? ld[0].y : c == 2 ? ld[0].z : ld[0].w);
      pk[1] = f2bf(c == 0 ? ld[1].x : c == 1 ? ld[1].y : c == 2 ? ld[1].z : ld[1].w);
      pk[2] = f2bf(c == 0 ? ld[2].x : c == 1 ? ld[2].y : c == 2 ? ld[2].z : ld[2].w);
      pk[3] = f2bf(c == 0 ? ld[3].x : c == 1 ? ld[3].y : c == 2 ? ld[3].z : ld[3].w);
      pk[4] = f2bf(c == 0 ? ld[4].x : c == 1 ? ld[4].y : c == 2 ? ld[4].z : ld[4].w);
      pk[5] = f2bf(c == 0 ? ld[5].x : c == 1 ? ld[5].y : c == 2 ? ld[5].z : ld[5].w);
      pk[6] = f2bf(c == 0 ? ld[6].x : c == 1 ? ld[6].y : c == 2 ? ld[6].z : ld[6].w);
      pk[7] = f2bf(c == 0 ? ld[7].x : c == 1 ? ld[7].y : c == 2 ? ld[7].z : ld[7].w);
      *(short8*)(ldst + c * PK) = pk;
    }
    __syncthreads();

    // ---- fragments + MFMA ----
    bfrag af[4], bf[4];
#pragma unroll
    for (int i = 0; i < 4; ++i)
      af[i] = *(const bfrag*)&Al[(wm * 64 + i * 16 + lm) * PK + q * 8];
#pragma unroll
    for (int j = 0; j < 4; ++j)
      bf[j] = *(const bfrag*)&Bl[(wn * 64 + j * 16 + lm) * PK + q * 8];
#pragma unroll
    for (int i = 0; i < 4; ++i)
#pragma unroll
      for (int j = 0; j < 4; ++j)
        acc[i][j] = __builtin_amdgcn_mfma_f32_16x16x32_bf16(af[i], bf[j], acc[i][j], 0, 0, 0);
  }

  float* Mb = Mws + (size_t)bb * DMODEL * DMODEL;
#pragma unroll
  for (int i = 0; i < 4; ++i)
#pragma unroll
    for (int j = 0; j < 4; ++j)
#pragma unroll
      for (int r = 0; r < 4; ++r) {
        const int row = mt * BM + wm * 64 + i * 16 + q * 4 + r;   // d'
        const int col = nt * BN + wn * 64 + j * 16 + lm;          // d
        atomAddF(&Mb[(size_t)row * DMODEL + col], acc[i][j][r]);
      }

  if (isB && mt == 0) {
    float* vp = &vws[bb * DMODEL + nt * BN + col4];
    atomAddF(vp + 0, vacc4.x);
    atomAddF(vp + 1, vacc4.y);
    atomAddF(vp + 2, vacc4.z);
    atomAddF(vp + 3, vacc4.w);
  }
}

// ---------------------------------------------------------------------------
// Kernel 2: C[b][s][d] = sum_{d'} W[s][d'] * M[b][d'][d] + bias[s]*v[b][d]
// 64x64 tiles, split-K=4, atomic epilogue into zeroed d_out.
// ---------------------------------------------------------------------------
__global__ __launch_bounds__(256) void gemm_c_kernel(
    const float* __restrict__ Wmat, const float* __restrict__ bias,
    const float* __restrict__ Mws, const float* __restrict__ vws,
    float* __restrict__ out)
{
  __shared__ short Wl[CBM * PK];
  __shared__ short Ml[CBN * PK];

  const int blk = blockIdx.x;          // grid = NBATCH * CSPLIT * 64 = 1024
  const int nt  = blk & 7;
  const int mt  = (blk >> 3) & 7;
  const int kt  = (blk >> 6) & (CSPLIT - 1);
  const int bb  = blk >> 8;

  const int tid = threadIdx.x;
  // W staging: row = tid>>2 (0..63), seg = tid&3 -> 8 k-floats
  const int arow  = tid >> 2;
  const int aseg  = tid & 3;
  // M staging (transpose): n = tid&63, kh = tid>>6 -> 8 k-rows
  const int ncol  = tid & 63;
  const int kh    = tid >> 6;

  const int wv   = tid >> 6;           // wave -> 16-row m-group
  const int lane = tid & 63;
  const int lm   = lane & 15, q = lane >> 4;

  const float* Mb = Mws + (size_t)bb * DMODEL * DMODEL;

  facc acc[4];
#pragma unroll
  for (int j = 0; j < 4; ++j) acc[j] = (facc){0.f, 0.f, 0.f, 0.f};

  const int ks = kt * CKC;
  for (int k0 = ks; k0 < ks + CKC; k0 += CBK) {
    // W: two float4 per thread (k-contiguous)
    float4 w0 = *(const float4*)&Wmat[(size_t)(mt * CBM + arow) * DMODEL + k0 + aseg * 8];
    float4 w1 = *(const float4*)&Wmat[(size_t)(mt * CBM + arow) * DMODEL + k0 + aseg * 8 + 4];
    // M: 8 scalar strided loads (column ncol)
    float mv[8];
    const float* mrow = Mb + (size_t)(k0 + kh * 8) * DMODEL + nt * CBN + ncol;
#pragma unroll
    for (int r = 0; r < 8; ++r) mv[r] = mrow[(size_t)r * DMODEL];

    __syncthreads();
    short8 pw;
    pw[0] = f2bf(w0.x); pw[1] = f2bf(w0.y); pw[2] = f2bf(w0.z); pw[3] = f2bf(w0.w);
    pw[4] = f2bf(w1.x); pw[5] = f2bf(w1.y); pw[6] = f2bf(w1.z); pw[7] = f2bf(w1.w);
    *(short8*)&Wl[arow * PK + aseg * 8] = pw;
    short8 pm;
#pragma unroll
    for (int r = 0; r < 8; ++r) pm[r] = f2bf(mv[r]);
    *(short8*)&Ml[ncol * PK + kh * 8] = pm;
    __syncthreads();

    bfrag af, bf[4];
    af = *(const bfrag*)&Wl[(wv * 16 + lm) * PK + q * 8];
#pragma unroll
    for (int j = 0; j < 4; ++j)
      bf[j] = *(const bfrag*)&Ml[(j * 16 + lm) * PK + q * 8];
#pragma unroll
    for (int j = 0; j < 4; ++j)
      acc[j] = __builtin_amdgcn_mfma_f32_16x16x32_bf16(af, bf[j], acc[j], 0, 0, 0);
  }

#pragma unroll
  for (int j = 0; j < 4; ++j)
#pragma unroll
    for (int r = 0; r < 4; ++r) {
      const int row = mt * CBM + wv * 16 + q * 4 + r;   // s
      const int col = nt * CBN + j * 16 + lm;           // d
      float val = acc[j][r];
      if (kt == 0) val += bias[row] * vws[bb * DMODEL + col];
      atomAddF(&out[((size_t)bb * DMODEL + row) * DMODEL + col], val);
    }
}

// ---------------------------------------------------------------------------
extern "C" void kernel_launch(void* const* d_in, const int* in_sizes, int n_in,
                              void* d_out, int out_size, void* d_ws, size_t ws_size,
                              hipStream_t stream) {
  const float* h    = (const float*)d_in[0];   // (4, 8192, 512) fp32
  const float* e    = (const float*)d_in[1];   // (4, 8192, 512) fp32
  const float* Wmat = (const float*)d_in[2];   // (512, 512) fp32
  const float* bias = (const float*)d_in[3];   // (512,) fp32
  float* out = (float*)d_out;                  // (4, 512, 512) fp32

  float* Mws = (float*)d_ws;                                            // 4 MB
  float* vws = (float*)((char*)d_ws + (size_t)NBATCH * DMODEL * DMODEL * sizeof(float)); // 8 KB
  const size_t zero_ws = (size_t)NBATCH * DMODEL * DMODEL * sizeof(float)
                       + (size_t)NBATCH * DMODEL * sizeof(float);
  hipMemsetAsync(d_ws, 0, zero_ws, stream);
  hipMemsetAsync(d_out, 0, (size_t)out_size * sizeof(float), stream);

  gemm_m_kernel<<<NBATCH * NKSPLIT * 16, 256, 0, stream>>>(h, e, Mws, vws);
  gemm_c_kernel<<<NBATCH * CSPLIT * 64, 256, 0, stream>>>(Wmat, bias, Mws, vws, out);
}

// Round 4
// 200.631 us; speedup vs baseline: 1.3522x; 1.2577x over previous
//
#include <hip/hip_runtime.h>
#include <math.h>
#include <stdint.h>

// Problem constants (fixed by the reference)
#define S_LEN  8192
#define DMODEL 512
#define NBATCH 4

// gemm_m tiling
constexpr int BM = 128, BN = 128, BK = 32;
constexpr int PK = 40;                    // padded LDS row stride (shorts); 80 B = 16B-aligned
constexpr int NSPLIT = 8;                 // split-K chunks for gemm_m
constexpr int KCHUNK = S_LEN / NSPLIT;    // 1024 -> 32 K-iters per block

// gemm_c tiling
constexpr int CBK = 32;
constexpr int PKC = 40;

// Workspace layout (bytes):
//   Mred  @ 0          : 4 MB   (4 x 512 x 512 f32)
//   vws   @ 4MB        : 8 KB   (4 x 512 f32)
//   Mpart @ 4MB+8KB    : 32 MB  (512 tiles x 16384 f32)   [primary path only]
//   vpart @ 36MB+8KB   : 256 KB (128 x 512 f32)           [primary path only]
constexpr size_t MRED_OFF  = 0;
constexpr size_t VWS_OFF   = (size_t)NBATCH * DMODEL * DMODEL * 4;          // 4 MB
constexpr size_t MPART_OFF = VWS_OFF + (size_t)NBATCH * DMODEL * 4;         // +8 KB
constexpr size_t VPART_OFF = MPART_OFF + (size_t)NBATCH * NSPLIT * 16 * 16384 * 4; // +32 MB
constexpr size_t WS_NEED   = VPART_OFF + (size_t)128 * 512 * 4;             // +256 KB

typedef short bfrag  __attribute__((ext_vector_type(8)));   // 8 bf16 (4 VGPRs)
typedef short short8 __attribute__((ext_vector_type(8)));
typedef short short4v __attribute__((ext_vector_type(4)));
typedef float facc   __attribute__((ext_vector_type(4)));   // 4 fp32 acc

__device__ __forceinline__ short f2bf(float f) {
  union { float f; unsigned u; } c; c.f = f;
  unsigned u = c.u;
  u = (u + 0x7fffu + ((u >> 16) & 1u)) >> 16;   // RNE
  return (short)(unsigned short)u;
}

__device__ __forceinline__ void atomAddF(float* p, float v) {
  unsafeAtomicAdd(p, v);
}

__device__ __forceinline__ float selc(const float4& v, int c) {
  return c == 0 ? v.x : c == 1 ? v.y : c == 2 ? v.z : v.w;
}

// ---------------------------------------------------------------------------
// Kernel 1: partial M[b][d'][d] = sum_{t in chunk} w_t h[b][t][d'] e[b][t][d]
// Register-prefetch pipeline: convert current tile to bf16 (freeing the load
// registers), issue next tile's loads, then barrier/LDS-write/barrier/MFMA.
// ATOMIC=false: plain stores to Mpart/vpart (reduced later).
// ATOMIC=true : atomicAdd into Mred/vws (fallback if ws too small).
// ---------------------------------------------------------------------------
template <bool ATOMIC>
__global__ __launch_bounds__(256, 2) void gemm_m_kernel(
    const float* __restrict__ h, const float* __restrict__ e,
    float* __restrict__ Mout, float* __restrict__ vout)
{
  __shared__ short Al[BM * PK];
  __shared__ short Bl[BN * PK];

  const int blk = blockIdx.x;          // grid = NBATCH * NSPLIT * 16 = 512
  const int nt  = blk & 3;
  const int mt  = (blk >> 2) & 3;
  const int kt  = (blk >> 4) & (NSPLIT - 1);
  const int bb  = blk / (16 * NSPLIT);

  const int tid   = threadIdx.x;
  const bool isB  = (tid >= 128);      // wave-uniform (waves 2,3)
  const int hid   = tid & 127;
  const int col4  = (hid & 31) * 4;    // 4-col group within the 128-wide tile
  const int trow  = hid >> 5;          // 0..3 -> t-rows trow*8 .. trow*8+7

  const int wv   = tid >> 6;           // wave 0..3 -> 2x2 of 64x64 subtiles
  const int wm   = wv >> 1, wn = wv & 1;
  const int lane = tid & 63;
  const int lm   = lane & 15, q = lane >> 4;

  const float* src = (isB ? e : h) + (size_t)bb * S_LEN * DMODEL
                   + (isB ? nt * BN : mt * BM) + col4;
  short* ldst = (isB ? Bl : Al) + col4 * PK + trow * 8;

  facc acc[4][4];
#pragma unroll
  for (int i = 0; i < 4; ++i)
#pragma unroll
    for (int j = 0; j < 4; ++j) acc[i][j] = (facc){0.f, 0.f, 0.f, 0.f};

  const float lnA = -(float)M_PI / (float)S_LEN;   // log(alpha), negative
  const int tstart = kt * KCHUNK, tend = tstart + KCHUNK;

  float wbase = __expf(lnA * (float)(S_LEN - 1 - tstart - trow * 8));
  const float stepw = __expf(-lnA * (float)BK);    // alpha^(-32)
  float cr[8];
#pragma unroll
  for (int r = 0; r < 8; ++r)
    cr[r] = __expf(-lnA * (float)r);               // alpha^(-r)

  float4 vacc4 = {0.f, 0.f, 0.f, 0.f};

  // ---- preload iter 0 ----
  float4 cur[8];
  {
    const float* p = src + (size_t)(tstart + trow * 8) * DMODEL;
#pragma unroll
    for (int r = 0; r < 8; ++r) cur[r] = *(const float4*)(p + (size_t)r * DMODEL);
  }

  for (int t0 = tstart; t0 < tend; t0 += BK) {
    // ---- scale (B only) + v accumulate; convert to bf16 packs (frees cur) ----
    if (isB) {
#pragma unroll
      for (int r = 0; r < 8; ++r) {
        const float w = wbase * cr[r];
        cur[r].x *= w; cur[r].y *= w; cur[r].z *= w; cur[r].w *= w;
      }
      if (mt == 0) {
#pragma unroll
        for (int r = 0; r < 8; ++r) {
          vacc4.x += cur[r].x; vacc4.y += cur[r].y;
          vacc4.z += cur[r].z; vacc4.w += cur[r].w;
        }
      }
    }
    wbase *= stepw;

    short8 pk[4];
#pragma unroll
    for (int c = 0; c < 4; ++c)
#pragma unroll
      for (int r = 0; r < 8; ++r) pk[c][r] = f2bf(selc(cur[r], c));

    // ---- issue next tile's loads (prefetch distance ~= one iteration) ----
    if (t0 + BK < tend) {
      const float* p = src + (size_t)(t0 + BK + trow * 8) * DMODEL;
#pragma unroll
      for (int r = 0; r < 8; ++r) cur[r] = *(const float4*)(p + (size_t)r * DMODEL);
    }

    __syncthreads();   // previous iteration's frag reads done
#pragma unroll
    for (int c = 0; c < 4; ++c)
      *(short8*)(ldst + c * PK) = pk[c];
    __syncthreads();

    bfrag af[4], bf[4];
#pragma unroll
    for (int i = 0; i < 4; ++i)
      af[i] = *(const bfrag*)&Al[(wm * 64 + i * 16 + lm) * PK + q * 8];
#pragma unroll
    for (int j = 0; j < 4; ++j)
      bf[j] = *(const bfrag*)&Bl[(wn * 64 + j * 16 + lm) * PK + q * 8];
#pragma unroll
    for (int i = 0; i < 4; ++i)
#pragma unroll
      for (int j = 0; j < 4; ++j)
        acc[i][j] = __builtin_amdgcn_mfma_f32_16x16x32_bf16(af[i], bf[j], acc[i][j], 0, 0, 0);
  }

  if (ATOMIC) {
    float* Mb = Mout + (size_t)bb * DMODEL * DMODEL;
#pragma unroll
    for (int i = 0; i < 4; ++i)
#pragma unroll
      for (int j = 0; j < 4; ++j)
#pragma unroll
        for (int r = 0; r < 4; ++r) {
          const int row = mt * BM + wm * 64 + i * 16 + q * 4 + r;
          const int col = nt * BN + wn * 64 + j * 16 + lm;
          atomAddF(&Mb[(size_t)row * DMODEL + col], acc[i][j][r]);
        }
    if (isB && mt == 0) {
      float* vp = &vout[bb * DMODEL + nt * BN + col4];
      atomAddF(vp + 0, vacc4.x); atomAddF(vp + 1, vacc4.y);
      atomAddF(vp + 2, vacc4.z); atomAddF(vp + 3, vacc4.w);
    }
  } else {
    // plain stores: tile-local layout, tile identity = blk
    float* Mp = Mout + (size_t)blk * (BM * BN);
#pragma unroll
    for (int i = 0; i < 4; ++i)
#pragma unroll
      for (int j = 0; j < 4; ++j)
#pragma unroll
        for (int r = 0; r < 4; ++r) {
          const int row = wm * 64 + i * 16 + q * 4 + r;   // local d'
          const int col = wn * 64 + j * 16 + lm;          // local d
          Mp[row * BN + col] = acc[i][j][r];
        }
    if (isB && mt == 0) {
      // vpart row = kt*16 + bb*4 + trow, col = nt*128 + col4
      *(float4*)&vout[(size_t)((kt * NBATCH + bb) * 4 + trow) * DMODEL
                      + nt * BN + col4] = vacc4;
    }
  }
}

// ---------------------------------------------------------------------------
// Reduce: Mred = sum_kt Mpart; vws = sum_{kt,trow} vpart.  262144 threads.
// ---------------------------------------------------------------------------
__global__ __launch_bounds__(256) void reduce_kernel(
    const float* __restrict__ Mpart, const float* __restrict__ vpart,
    float* __restrict__ Mred, float* __restrict__ vws)
{
  const int gid = blockIdx.x * 256 + threadIdx.x;    // 0 .. 262143 (one float4 each)
  const int bb     = gid >> 16;          // 65536 float4 per batch
  const int rem    = gid & 65535;
  const int tile   = rem >> 12;          // 16 tiles (mt*4+nt)
  const int within = rem & 4095;         // float4 index inside 128x128 tile

  const size_t base = ((size_t)((bb << 7) | tile)) * (BM * BN) + (size_t)within * 4;
  float4 s = {0.f, 0.f, 0.f, 0.f};
#pragma unroll
  for (int kt = 0; kt < NSPLIT; ++kt) {
    const float4 v = *(const float4*)&Mpart[base + (size_t)(kt << 4) * (BM * BN)];
    s.x += v.x; s.y += v.y; s.z += v.z; s.w += v.w;
  }
  const int r = within >> 5;             // local row 0..127
  const int c = (within & 31) * 4;       // local col (float4-aligned)
  const int mt = tile >> 2, nt = tile & 3;
  *(float4*)&Mred[(size_t)bb * DMODEL * DMODEL
                  + (size_t)(mt * BM + r) * DMODEL + nt * BN + c] = s;

  if (gid < (NBATCH * DMODEL / 4)) {     // 512 threads: v reduction
    const int vb = gid >> 7;             // batch
    const int vc = (gid & 127) * 4;      // col (float4)
    float4 vs = {0.f, 0.f, 0.f, 0.f};
    for (int row = 0; row < NSPLIT * NBATCH; ++row) {   // kt x trow pairs for vb
      // rows used: (kt*NBATCH + vb)*4 + trow, kt=0..7, trow=0..3
    }
#pragma unroll
    for (int kt = 0; kt < NSPLIT; ++kt)
#pragma unroll
      for (int tr = 0; tr < 4; ++tr) {
        const float4 v = *(const float4*)&vpart[(size_t)((kt * NBATCH + vb) * 4 + tr) * DMODEL + vc];
        vs.x += v.x; vs.y += v.y; vs.z += v.z; vs.w += v.w;
      }
    *(float4*)&vws[vb * DMODEL + vc] = vs;
  }
}

// ---------------------------------------------------------------------------
// Kernel 3: C[b][s][d] = sum_{d'} W[s][d'] Mred[b][d'][d] + bias[s]*v[b][d]
// 64x64 tiles, K=512, 16 pipelined iters, plain stores.
// ---------------------------------------------------------------------------
__global__ __launch_bounds__(256) void gemm_c_kernel(
    const float* __restrict__ Wmat, const float* __restrict__ bias,
    const float* __restrict__ Mred, const float* __restrict__ vws,
    float* __restrict__ out)
{
  __shared__ short Wl[64 * PKC];
  __shared__ short Ml[64 * PKC];

  const int blk = blockIdx.x;          // grid = 4 * 8 * 8 = 256
  const int ntc = blk & 7;
  const int mtc = (blk >> 3) & 7;
  const int bb  = blk >> 6;

  const int tid  = threadIdx.x;
  const bool isM = (tid >= 128);
  const int hid  = tid & 127;
  // W-half: row = hid&63, k-half = hid>>6 (16 k each)
  const int arow = hid & 63;
  const int ahalf = (hid >> 6) * 16;
  // M-half: col4 = (hid&15)*4, 4 k-rows starting at (hid>>4)*4
  const int mcol4 = (hid & 15) * 4;
  const int mrow4 = (hid >> 4) * 4;

  const int wv   = tid >> 6;
  const int lane = tid & 63;
  const int lm   = lane & 15, q = lane >> 4;

  const float* Mb = Mred + (size_t)bb * DMODEL * DMODEL;

  facc acc[4];
#pragma unroll
  for (int j = 0; j < 4; ++j) acc[j] = (facc){0.f, 0.f, 0.f, 0.f};

  // ---- preload iter 0: 4 float4 per thread ----
  float4 cur[4];
  if (!isM) {
    const float* p = &Wmat[(size_t)(mtc * 64 + arow) * DMODEL + ahalf];
#pragma unroll
    for (int r = 0; r < 4; ++r) cur[r] = *(const float4*)(p + r * 4);
  } else {
    const float* p = Mb + (size_t)mrow4 * DMODEL + ntc * 64 + mcol4;
#pragma unroll
    for (int r = 0; r < 4; ++r) cur[r] = *(const float4*)(p + (size_t)r * DMODEL);
  }

  for (int k0 = 0; k0 < DMODEL; k0 += CBK) {
    // ---- convert current (frees cur) ----
    short8 pw0, pw1;           // W-half packs
    short4v pm[4];             // M-half packs (transposed)
    if (!isM) {
      pw0[0] = f2bf(cur[0].x); pw0[1] = f2bf(cur[0].y); pw0[2] = f2bf(cur[0].z); pw0[3] = f2bf(cur[0].w);
      pw0[4] = f2bf(cur[1].x); pw0[5] = f2bf(cur[1].y); pw0[6] = f2bf(cur[1].z); pw0[7] = f2bf(cur[1].w);
      pw1[0] = f2bf(cur[2].x); pw1[1] = f2bf(cur[2].y); pw1[2] = f2bf(cur[2].z); pw1[3] = f2bf(cur[2].w);
      pw1[4] = f2bf(cur[3].x); pw1[5] = f2bf(cur[3].y); pw1[6] = f2bf(cur[3].z); pw1[7] = f2bf(cur[3].w);
    } else {
#pragma unroll
      for (int c = 0; c < 4; ++c) {
        pm[c][0] = f2bf(selc(cur[0], c)); pm[c][1] = f2bf(selc(cur[1], c));
        pm[c][2] = f2bf(selc(cur[2], c)); pm[c][3] = f2bf(selc(cur[3], c));
      }
    }

    // ---- issue next iter's loads ----
    if (k0 + CBK < DMODEL) {
      if (!isM) {
        const float* p = &Wmat[(size_t)(mtc * 64 + arow) * DMODEL + k0 + CBK + ahalf];
#pragma unroll
        for (int r = 0; r < 4; ++r) cur[r] = *(const float4*)(p + r * 4);
      } else {
        const float* p = Mb + (size_t)(k0 + CBK + mrow4) * DMODEL + ntc * 64 + mcol4;
#pragma unroll
        for (int r = 0; r < 4; ++r) cur[r] = *(const float4*)(p + (size_t)r * DMODEL);
      }
    }

    __syncthreads();
    if (!isM) {
      *(short8*)&Wl[arow * PKC + ahalf]     = pw0;
      *(short8*)&Wl[arow * PKC + ahalf + 8] = pw1;
    } else {
#pragma unroll
      for (int c = 0; c < 4; ++c)
        *(short4v*)&Ml[(mcol4 + c) * PKC + mrow4] = pm[c];
    }
    __syncthreads();

    bfrag af, bf[4];
    af = *(const bfrag*)&Wl[(wv * 16 + lm) * PKC + q * 8];
#pragma unroll
    for (int j = 0; j < 4; ++j)
      bf[j] = *(const bfrag*)&Ml[(j * 16 + lm) * PKC + q * 8];
#pragma unroll
    for (int j = 0; j < 4; ++j)
      acc[j] = __builtin_amdgcn_mfma_f32_16x16x32_bf16(af, bf[j], acc[j], 0, 0, 0);
  }

#pragma unroll
  for (int j = 0; j < 4; ++j)
#pragma unroll
    for (int r = 0; r < 4; ++r) {
      const int row = mtc * 64 + wv * 16 + q * 4 + r;   // s
      const int col = ntc * 64 + j * 16 + lm;           // d
      out[((size_t)bb * DMODEL + row) * DMODEL + col] =
          acc[j][r] + bias[row] * vws[bb * DMODEL + col];
    }
}

// ---------------------------------------------------------------------------
extern "C" void kernel_launch(void* const* d_in, const int* in_sizes, int n_in,
                              void* d_out, int out_size, void* d_ws, size_t ws_size,
                              hipStream_t stream) {
  const float* h    = (const float*)d_in[0];   // (4, 8192, 512) fp32
  const float* e    = (const float*)d_in[1];   // (4, 8192, 512) fp32
  const float* Wmat = (const float*)d_in[2];   // (512, 512) fp32
  const float* bias = (const float*)d_in[3];   // (512,) fp32
  float* out = (float*)d_out;                  // (4, 512, 512) fp32

  float* Mred  = (float*)((char*)d_ws + MRED_OFF);
  float* vws   = (float*)((char*)d_ws + VWS_OFF);
  float* Mpart = (float*)((char*)d_ws + MPART_OFF);
  float* vpart = (float*)((char*)d_ws + VPART_OFF);

  if (ws_size >= WS_NEED) {
    // primary: store partials, reduce, gemm_c — no memsets, no M atomics
    gemm_m_kernel<false><<<NBATCH * NSPLIT * 16, 256, 0, stream>>>(h, e, Mpart, vpart);
    reduce_kernel<<<1024, 256, 0, stream>>>(Mpart, vpart, Mred, vws);
  } else {
    // fallback: atomics into zeroed Mred/vws
    hipMemsetAsync(d_ws, 0, VWS_OFF + (size_t)NBATCH * DMODEL * 4, stream);
    gemm_m_kernel<true><<<NBATCH * NSPLIT * 16, 256, 0, stream>>>(h, e, Mred, vws);
  }
  gemm_c_kernel<<<NBATCH * 64, 256, 0, stream>>>(Wmat, bias, Mred, vws, out);
}